// Round 5
// baseline (2010.191 us; speedup 1.0000x reference)
//
#include <hip/hip_runtime.h>
#include <math.h>

#define N_NODES 100000
#define N_EDGES 1600000
#define DIM     128
#define NPOOL0  50000
#define NPOOL1  25000
#define NGRAPH  64

typedef __attribute__((ext_vector_type(8))) short short8;
typedef __attribute__((ext_vector_type(4))) float f32x4;

__device__ __forceinline__ float lrelu(float v) { return v > 0.f ? v : 0.01f * v; }

// f32 -> bf16 round-to-nearest-even
__device__ __forceinline__ unsigned short f2bf(float f) {
    unsigned u = __float_as_uint(f);
    unsigned r = u + 0x7FFFu + ((u >> 16) & 1u);
    return (unsigned short)(r >> 16);
}

// ---------------- fills ----------------
__global__ __launch_bounds__(256) void fill_f32(float* __restrict__ p, int n, float v) {
    int i = blockIdx.x * 256 + threadIdx.x;
    if (i < n) p[i] = v;
}
__global__ __launch_bounds__(256) void fill_i32(int* __restrict__ p, int n, int v) {
    int i = blockIdx.x * 256 + threadIdx.x;
    if (i < n) p[i] = v;
}
__global__ __launch_bounds__(256) void conv_bf16(const float* __restrict__ in, unsigned short* __restrict__ out, int n) {
    int i = blockIdx.x * 256 + threadIdx.x;
    if (i < n) out[i] = f2bf(in[i]);
}

// ---------------- MFMA 2-layer MLP: Y = lrelu((X@W1^T+b1)*g+be) @ W2^T + b2 ----------------
// 64 rows/block, 4 waves, wave owns 16-row strip (no cross-wave deps between layers).
// A-frags from LDS bf16 (stride KIN+8 -> conflict-free b128), B-frags straight from
// bf16 weights in global (L2-resident). mfma_f32_16x16x32_bf16:
//   A: lane l holds row=l&15, k=8*(l>>4)+j ; B: col=l&15, k=8*(l>>4)+j ; D: col=l&15,row=4*(l>>4)+q
template<int KIN, int HID, bool BF16IN>
__global__ __launch_bounds__(256) void mlp_mfma(
        const void* __restrict__ Xv, int R,
        const unsigned short* __restrict__ W1, const float* __restrict__ B1,
        const float* __restrict__ G1, const float* __restrict__ BE1,
        const unsigned short* __restrict__ W2, const float* __restrict__ B2,
        unsigned short* __restrict__ Y)
{
    constexpr int XS_S = KIN + 8;
    constexpr int TS_S = HID + 8;
    __shared__ unsigned short xs[64 * XS_S];
    __shared__ unsigned short ts[64 * TS_S];

    const int tid = threadIdx.x;
    const int r0 = blockIdx.x * 64;

    // stage X tile -> bf16 LDS
    {
        const int row = tid >> 2;
        const int c0 = (tid & 3) * 32;
        const int gr = r0 + row;
        if (BF16IN) {
            const unsigned short* X = (const unsigned short*)Xv;
            #pragma unroll
            for (int q = 0; q < 4; ++q) {
                short8 v = short8{0,0,0,0,0,0,0,0};
                if (gr < R) v = *(const short8*)&X[(size_t)gr * KIN + c0 + q * 8];
                *(short8*)&xs[row * XS_S + c0 + q * 8] = v;
            }
        } else {
            const float* X = (const float*)Xv;
            #pragma unroll
            for (int q = 0; q < 4; ++q) {
                short8 v = short8{0,0,0,0,0,0,0,0};
                if (gr < R) {
                    float4 a = *(const float4*)&X[(size_t)gr * KIN + c0 + q * 8];
                    float4 b = *(const float4*)&X[(size_t)gr * KIN + c0 + q * 8 + 4];
                    v[0] = (short)f2bf(a.x); v[1] = (short)f2bf(a.y);
                    v[2] = (short)f2bf(a.z); v[3] = (short)f2bf(a.w);
                    v[4] = (short)f2bf(b.x); v[5] = (short)f2bf(b.y);
                    v[6] = (short)f2bf(b.z); v[7] = (short)f2bf(b.w);
                }
                *(short8*)&xs[row * XS_S + c0 + q * 8] = v;
            }
        }
    }
    __syncthreads();

    const int wv = tid >> 6;
    const int lane = tid & 63;
    const int lr = lane & 15;
    const int lq = lane >> 4;
    const int arow = wv * 16 + lr;

    // ---- layer 1 ----
    constexpr int NCG1 = HID / 16;
    constexpr int NK1 = KIN / 32;
    f32x4 acc1[NCG1] = {};
    for (int kc = 0; kc < NK1; ++kc) {
        short8 a = *(short8*)&xs[arow * XS_S + kc * 32 + lq * 8];
        #pragma unroll
        for (int cg = 0; cg < NCG1; ++cg) {
            short8 b = *(const short8*)&W1[(size_t)(cg * 16 + lr) * KIN + kc * 32 + lq * 8];
            acc1[cg] = __builtin_amdgcn_mfma_f32_16x16x32_bf16(a, b, acc1[cg], 0, 0, 0);
        }
    }
    #pragma unroll
    for (int cg = 0; cg < NCG1; ++cg) {
        const int c = cg * 16 + lr;
        const float bb = B1[c], gg = G1[c], ee = BE1[c];
        #pragma unroll
        for (int q = 0; q < 4; ++q) {
            const int rr = wv * 16 + lq * 4 + q;
            float v = (acc1[cg][q] + bb) * gg + ee;
            ts[rr * TS_S + c] = f2bf(lrelu(v));
        }
    }
    // wave-local rows: no barrier needed (compiler inserts lgkmcnt waits)

    // ---- layer 2 ----
    constexpr int NK2 = HID / 32;
    f32x4 acc2[8] = {};
    for (int kc = 0; kc < NK2; ++kc) {
        short8 a = *(short8*)&ts[arow * TS_S + kc * 32 + lq * 8];
        #pragma unroll
        for (int cg = 0; cg < 8; ++cg) {
            short8 b = *(const short8*)&W2[(size_t)(cg * 16 + lr) * HID + kc * 32 + lq * 8];
            acc2[cg] = __builtin_amdgcn_mfma_f32_16x16x32_bf16(a, b, acc2[cg], 0, 0, 0);
        }
    }
    #pragma unroll
    for (int cg = 0; cg < 8; ++cg) {
        const int c = cg * 16 + lr;
        const float bb = B2[c];
        #pragma unroll
        for (int q = 0; q < 4; ++q) {
            const int gr = r0 + wv * 16 + lq * 4 + q;
            if (gr < R) Y[(size_t)gr * 128 + c] = f2bf(acc2[cg][q] + bb);
        }
    }
}

// ---------------- CSR build ----------------
__global__ __launch_bounds__(256) void count0(const int* __restrict__ src, const int* __restrict__ dst,
                                              float* __restrict__ deg, int* __restrict__ cnt, int E) {
    int e = blockIdx.x * 256 + threadIdx.x;
    if (e < E) {
        atomicAdd(&deg[src[e]], 1.0f);
        atomicAdd(&cnt[dst[e]], 1);
    }
}
__global__ __launch_bounds__(256) void rsqrt_ip(float* __restrict__ p, int n) {
    int i = blockIdx.x * 256 + threadIdx.x;
    if (i < n) p[i] = rsqrtf(p[i]);
}
__global__ __launch_bounds__(256) void scan_blk(const int* __restrict__ cnt, int* __restrict__ offs,
                                                int* __restrict__ bsum, int n) {
    __shared__ int s[256];
    const int tid = threadIdx.x;
    const int i = blockIdx.x * 256 + tid;
    int v = (i < n) ? cnt[i] : 0;
    s[tid] = v;
    __syncthreads();
    #pragma unroll
    for (int d = 1; d < 256; d <<= 1) {
        int t = (tid >= d) ? s[tid - d] : 0;
        __syncthreads();
        s[tid] += t;
        __syncthreads();
    }
    if (i < n) offs[i] = s[tid] - v;
    if (tid == 255) bsum[blockIdx.x] = s[255];
}
__global__ __launch_bounds__(512) void scan_top(int* __restrict__ bsum, int nb) {
    __shared__ int s[512];
    const int tid = threadIdx.x;
    int v = (tid < nb) ? bsum[tid] : 0;
    s[tid] = v;
    __syncthreads();
    #pragma unroll
    for (int d = 1; d < 512; d <<= 1) {
        int t = (tid >= d) ? s[tid - d] : 0;
        __syncthreads();
        s[tid] += t;
        __syncthreads();
    }
    if (tid < nb) bsum[tid] = s[tid] - v;
}
__global__ __launch_bounds__(256) void scan_add(int* __restrict__ offs, const int* __restrict__ bsum,
                                                int* __restrict__ fill, int n) {
    int i = blockIdx.x * 256 + threadIdx.x;
    if (i < n) {
        int o = offs[i] + bsum[i >> 8];
        offs[i] = o;
        fill[i] = o;
    }
}
__global__ __launch_bounds__(256) void place_pack(const int* __restrict__ dst, const int* __restrict__ srcA,
                                                  const float* __restrict__ ea, const float* __restrict__ dis,
                                                  int* __restrict__ fill, int2* __restrict__ pack, int E) {
    int e = blockIdx.x * 256 + threadIdx.x;
    if (e < E) {
        int d = dst[e];
        int s = srcA[e];
        int pos = atomicAdd(&fill[d], 1);
        pack[pos] = make_int2(s, __float_as_int(dis[s] * ea[e]));
    }
}
__global__ __launch_bounds__(256) void edgemap(
        const int* __restrict__ ei0, const int* __restrict__ ei1,
        const int* __restrict__ c0, const int* __restrict__ c1,
        int* __restrict__ src2, int* __restrict__ dst2,
        float* __restrict__ deg2, int* __restrict__ cnt2, int E)
{
    int e = blockIdx.x * 256 + threadIdx.x;
    if (e < E) {
        int s = c1[c0[ei0[e]]];
        int d = c1[c0[ei1[e]]];
        src2[e] = s;
        dst2[e] = d;
        atomicAdd(&deg2[s], 1.0f);
        atomicAdd(&cnt2[d], 1);
    }
}
// counting-sort bookkeeping for member lists
__global__ __launch_bounds__(256) void seg_count(const int* __restrict__ map, int* __restrict__ cnt, int n) {
    int i = blockIdx.x * 256 + threadIdx.x;
    if (i < n) atomicAdd(&cnt[map[i]], 1);
}
__global__ __launch_bounds__(256) void place_idx(const int* __restrict__ map, int* __restrict__ fill,
                                                 int* __restrict__ list, int n) {
    int i = blockIdx.x * 256 + threadIdx.x;
    if (i < n) {
        int pos = atomicAdd(&fill[map[i]], 1);
        list[pos] = i;
    }
}
__global__ __launch_bounds__(256) void segmax_i32(const int* __restrict__ map, const int* __restrict__ vals,
                                                  int* __restrict__ out, int n) {
    int i = blockIdx.x * 256 + threadIdx.x;
    if (i < n) atomicMax(&out[map[i]], vals[i]);
}

// ---------------- gather-reduce (one wave per dst node; packed CSR; readlane broadcast) ----------------
#define EDGE_ITER(K, A0, A1) {                                                  \
    int s_ = __builtin_amdgcn_readlane(pv.x, (K));                              \
    float w_ = __int_as_float(__builtin_amdgcn_readlane(pv.y, (K)));            \
    unsigned hv_ = hrows[(size_t)s_ * 64 + lane];                               \
    float c_ = w_ * di;                                                         \
    A0 += c_ * __uint_as_float(hv_ << 16);                                      \
    A1 += c_ * __uint_as_float(hv_ & 0xFFFF0000u); }

// mpnn0 + residual: agg0[i] = bf16( dis^2*h[i] + sum + x[i] )  (plain row stores)
__global__ __launch_bounds__(256) void gather0(
        const unsigned short* __restrict__ h16, const float* __restrict__ x,
        const float* __restrict__ dis, const int* __restrict__ offs,
        const int* __restrict__ cnt, const int2* __restrict__ pack,
        unsigned* __restrict__ agg0)
{
    const int wid = (blockIdx.x * 256 + threadIdx.x) >> 6;
    if (wid >= N_NODES) return;
    const int lane = threadIdx.x & 63;
    const float di = dis[wid];
    const unsigned* hrows = (const unsigned*)h16;

    unsigned hself = hrows[(size_t)wid * 64 + lane];
    float a0 = di * di * __uint_as_float(hself << 16);
    float a1 = di * di * __uint_as_float(hself & 0xFFFF0000u);
    float b0 = 0.f, b1 = 0.f;

    const int base = offs[wid], n = cnt[wid];
    int k0 = 0;
    for (; k0 + 64 <= n; k0 += 64) {
        int2 pv = pack[base + k0 + lane];
        #pragma unroll
        for (int k = 0; k < 64; k += 2) {
            EDGE_ITER(k,     a0, a1);
            EDGE_ITER(k + 1, b0, b1);
        }
    }
    const int rem = n - k0;
    if (rem > 0) {
        int2 pv = (lane < rem) ? pack[base + k0 + lane] : make_int2(0, 0);
        #pragma unroll 4
        for (int k = 0; k < rem; ++k) EDGE_ITER(k, a0, a1);
    }
    a0 += b0; a1 += b1;

    float2 xv = *(const float2*)&x[(size_t)wid * DIM + lane * 2];
    agg0[(size_t)wid * 64 + lane] =
        ((unsigned)f2bf(a1 + xv.y) << 16) | (unsigned)f2bf(a0 + xv.x);
}

// mpnn2: agg2[i] = lrelu( dis^2*hm2[i] + sum )  (f32 row stores)
__global__ __launch_bounds__(256) void gather2(
        const unsigned short* __restrict__ hm2,
        const float* __restrict__ dis, const int* __restrict__ offs,
        const int* __restrict__ cnt, const int2* __restrict__ pack,
        float* __restrict__ agg2)
{
    const int wid = (blockIdx.x * 256 + threadIdx.x) >> 6;
    if (wid >= NPOOL1) return;
    const int lane = threadIdx.x & 63;
    const float di = dis[wid];
    const unsigned* hrows = (const unsigned*)hm2;

    unsigned hself = hrows[(size_t)wid * 64 + lane];
    float a0 = di * di * __uint_as_float(hself << 16);
    float a1 = di * di * __uint_as_float(hself & 0xFFFF0000u);
    float b0 = 0.f, b1 = 0.f;

    const int base = offs[wid], n = cnt[wid];
    int k0 = 0;
    for (; k0 + 64 <= n; k0 += 64) {
        int2 pv = pack[base + k0 + lane];
        #pragma unroll
        for (int k = 0; k < 64; k += 2) {
            EDGE_ITER(k,     a0, a1);
            EDGE_ITER(k + 1, b0, b1);
        }
    }
    const int rem = n - k0;
    if (rem > 0) {
        int2 pv = (lane < rem) ? pack[base + k0 + lane] : make_int2(0, 0);
        #pragma unroll 4
        for (int k = 0; k < rem; ++k) EDGE_ITER(k, a0, a1);
    }
    a0 += b0; a1 += b1;

    float2 o = make_float2(lrelu(a0), lrelu(a1));
    *(float2*)&agg2[(size_t)wid * DIM + lane * 2] = o;
}

// ---------------- pool gathers (atomic-free segment max via member lists) ----------------
// pool1: h2[c] = fix(max lrelu(agg0[members])) + fix(max x[members])
__global__ __launch_bounds__(256) void pool1_gather(
        const unsigned* __restrict__ agg0, const float* __restrict__ x,
        const int* __restrict__ offsc, const int* __restrict__ cntc,
        const int* __restrict__ listc, unsigned* __restrict__ h2)
{
    const int c = (blockIdx.x * 256 + threadIdx.x) >> 6;
    if (c >= NPOOL0) return;
    const int lane = threadIdx.x & 63;
    const int base = offsc[c], n = cntc[c];
    float p0 = -INFINITY, p1 = -INFINITY, o0 = -INFINITY, o1 = -INFINITY;
    for (int k = 0; k < n; ++k) {
        const int node = listc[base + k];
        const unsigned hv = agg0[(size_t)node * 64 + lane];
        const float2 xv = *(const float2*)&x[(size_t)node * 128 + lane * 2];
        p0 = fmaxf(p0, lrelu(__uint_as_float(hv << 16)));
        p1 = fmaxf(p1, lrelu(__uint_as_float(hv & 0xFFFF0000u)));
        o0 = fmaxf(o0, xv.x);
        o1 = fmaxf(o1, xv.y);
    }
    p0 = (p0 == -INFINITY) ? 0.f : p0;
    p1 = (p1 == -INFINITY) ? 0.f : p1;
    o0 = (o0 == -INFINITY) ? 0.f : o0;
    o1 = (o1 == -INFINITY) ? 0.f : o1;
    h2[(size_t)c * 64 + lane] =
        ((unsigned)f2bf(p1 + o1) << 16) | (unsigned)f2bf(p0 + o0);
}

// pool2: x2[d] = fix(max lrelu(h2[members]))   (bf16 out, feeds mlp2)
__global__ __launch_bounds__(256) void pool2_gather(
        const unsigned* __restrict__ h2,
        const int* __restrict__ offsd, const int* __restrict__ cntd,
        const int* __restrict__ listd, unsigned* __restrict__ x2)
{
    const int d = (blockIdx.x * 256 + threadIdx.x) >> 6;
    if (d >= NPOOL1) return;
    const int lane = threadIdx.x & 63;
    const int base = offsd[d], n = cntd[d];
    float m0 = -INFINITY, m1 = -INFINITY;
    for (int k = 0; k < n; ++k) {
        const int node = listd[base + k];
        const unsigned hv = h2[(size_t)node * 64 + lane];
        m0 = fmaxf(m0, lrelu(__uint_as_float(hv << 16)));
        m1 = fmaxf(m1, lrelu(__uint_as_float(hv & 0xFFFF0000u)));
    }
    m0 = (m0 == -INFINITY) ? 0.f : m0;
    m1 = (m1 == -INFINITY) ? 0.f : m1;
    x2[(size_t)d * 64 + lane] = ((unsigned)f2bf(m1) << 16) | (unsigned)f2bf(m0);
}

// ---------------- head (fused global max pool + MLP head) ----------------
__global__ __launch_bounds__(128) void head_fused(
        const float* __restrict__ agg2,
        const int* __restrict__ offsg, const int* __restrict__ cntg, const int* __restrict__ listg,
        const float* __restrict__ energy,
        const float* __restrict__ emb_w, const float* __restrict__ emb_b,
        const float* __restrict__ emb_g, const float* __restrict__ emb_be,
        const float* __restrict__ lw1, const float* __restrict__ lb1,
        const float* __restrict__ lg, const float* __restrict__ lbe,
        const float* __restrict__ lw2, const float* __restrict__ lb2,
        float* __restrict__ out)
{
    const int g = blockIdx.x;
    const int t = threadIdx.x;
    __shared__ float z[136];
    __shared__ float red[128];

    const int base = offsg[g], n = cntg[g];
    float m = -INFINITY;
    for (int k = 0; k < n; ++k) {
        const int node = listg[base + k];
        m = fmaxf(m, agg2[(size_t)node * 128 + t]);
    }
    z[t] = (m == -INFINITY) ? 0.f : m;
    if (t < 8) {
        float s = 0.f;
        #pragma unroll
        for (int k = 0; k < 21; ++k) s += energy[g * 21 + k] * emb_w[t * 21 + k];
        s = (s + emb_b[t]) * emb_g[t] + emb_be[t];
        z[128 + t] = lrelu(s);
    }
    __syncthreads();
    float s = 0.f;
    #pragma unroll 8
    for (int k = 0; k < 136; ++k) s += z[k] * lw1[t * 136 + k];
    float z2 = lrelu((s + lb1[t]) * lg[t] + lbe[t]);
    red[t] = z2 * lw2[t];
    __syncthreads();
    if (t == 0) {
        float acc = lb2[0];
        for (int k = 0; k < 128; ++k) acc += red[k];
        out[g] = acc;
    }
}

extern "C" void kernel_launch(void* const* d_in, const int* in_sizes, int n_in,
                              void* d_out, int out_size, void* d_ws, size_t ws_size,
                              hipStream_t stream) {
    const float* x        = (const float*)d_in[0];
    const float* edge_attr= (const float*)d_in[1];
    const float* energy   = (const float*)d_in[2];
    const float* w0a = (const float*)d_in[3];
    const float* b0a = (const float*)d_in[4];
    const float* g0  = (const float*)d_in[5];
    const float* be0 = (const float*)d_in[6];
    const float* w0b = (const float*)d_in[7];
    const float* b0b = (const float*)d_in[8];
    const float* w2a = (const float*)d_in[15];
    const float* b2a = (const float*)d_in[16];
    const float* g2  = (const float*)d_in[17];
    const float* be2 = (const float*)d_in[18];
    const float* w2b = (const float*)d_in[19];
    const float* b2b = (const float*)d_in[20];
    const float* emb_w  = (const float*)d_in[21];
    const float* emb_b  = (const float*)d_in[22];
    const float* emb_g  = (const float*)d_in[23];
    const float* emb_be = (const float*)d_in[24];
    const float* lw1 = (const float*)d_in[25];
    const float* lb1 = (const float*)d_in[26];
    const float* lg  = (const float*)d_in[27];
    const float* lbe = (const float*)d_in[28];
    const float* lw2 = (const float*)d_in[29];
    const float* lb2 = (const float*)d_in[30];
    const int* ei0   = (const int*)d_in[31];
    const int* ei1   = ei0 + N_EDGES;
    const int* batch = (const int*)d_in[32];
    const int* c0    = (const int*)d_in[33];
    const int* c1    = (const int*)d_in[34];
    float* out = (float*)d_out;

    // ---- workspace layout (peak ~87.3 MB; < 103.3 MB proven) ----
    char* ws = (char*)d_ws;
    unsigned short* h16 = (unsigned short*)(ws + 0);         // [N,128] bf16 (dead after gather0)
    int*   src2  = (int*)(ws + 0);                           // [E] (alias h16, written in edgemap)
    int*   dst2  = (int*)(ws + 6400000);                     // [E]
    float* agg2  = (float*)(ws + 12800000);                  // [N1,128] f32 (after src2/dst2 dead)
    unsigned* agg0 = (unsigned*)(ws + 25600000);             // [N,128] bf16 (dead after pool1_gather)
    unsigned short* hm2 = (unsigned short*)(ws + 25600000);  // [N1,128] bf16 (alias agg0)
    int2*  pack0 = (int2*)(ws + 51200000);                   // [E] (dead after gather0)
    int2*  pack2 = (int2*)(ws + 51200000);                   // alias
    unsigned* h2 = (unsigned*)(ws + 64000000);               // [N0,128] bf16
    unsigned* x2 = (unsigned*)(ws + 76800000);               // [N1,128] bf16
    float* deg0  = (float*)(ws + 83200000);
    int*   cnt0  = (int*)(ws + 83600000);
    int*   offs0 = (int*)(ws + 84000000);
    int*   fill0 = (int*)(ws + 84400000);
    int*   cntc  = (int*)(ws + 84800000);
    int*   offsc = (int*)(ws + 85000000);
    int*   fillc = (int*)(ws + 85200000);
    int*   listc = (int*)(ws + 85400000);                    // [N]
    int*   pb    = (int*)(ws + 85800000);
    int*   pb2   = (int*)(ws + 86000000);
    int*   cntd  = (int*)(ws + 86100000);
    int*   offsd = (int*)(ws + 86200000);
    int*   filld = (int*)(ws + 86300000);
    int*   listd = (int*)(ws + 86400000);                    // [N0]
    float* deg2  = (float*)(ws + 86600000);
    int*   cnt2  = (int*)(ws + 86700000);
    int*   offs2 = (int*)(ws + 86800000);
    int*   fill2 = (int*)(ws + 86900000);
    int*   cntg  = (int*)(ws + 87000000);                    // [64]
    int*   offsg = (int*)(ws + 87000256);
    int*   fillg = (int*)(ws + 87000512);
    int*   listg = (int*)(ws + 87001088);                    // [N1]
    int*   bsum  = (int*)(ws + 87102088 + 8);                // align
    unsigned short* w0a16 = (unsigned short*)(ws + 87105000);
    unsigned short* w0b16 = (unsigned short*)(ws + 87138000);
    unsigned short* w2a16 = (unsigned short*)(ws + 87171000);
    unsigned short* w2b16 = (unsigned short*)(ws + 87237000);

    (void)in_sizes; (void)n_in; (void)out_size; (void)ws_size;

    const int NB0 = (N_NODES + 255) / 256;   // 391
    const int NBC = (NPOOL0 + 255) / 256;    // 196
    const int NB1 = (NPOOL1 + 255) / 256;    // 98
    const int NBE = (N_EDGES + 255) / 256;

    // ---- weight conversion (bf16) ----
    conv_bf16<<<64, 256, 0, stream>>>(w0a, w0a16, 16384);
    conv_bf16<<<64, 256, 0, stream>>>(w0b, w0b16, 16384);
    conv_bf16<<<128, 256, 0, stream>>>(w2a, w2a16, 32768);
    conv_bf16<<<128, 256, 0, stream>>>(w2b, w2b16, 32768);

    // ---- mpnn0: MFMA MLP + CSR(pack) + gather ----
    fill_f32<<<NB0, 256, 0, stream>>>(deg0, N_NODES, 1.0f);
    fill_i32<<<NB0, 256, 0, stream>>>(cnt0, N_NODES, 0);
    mlp_mfma<128, 128, false><<<(N_NODES + 63) / 64, 256, 0, stream>>>(
        x, N_NODES, w0a16, b0a, g0, be0, w0b16, b0b, h16);
    count0<<<NBE, 256, 0, stream>>>(ei0, ei1, deg0, cnt0, N_EDGES);
    rsqrt_ip<<<NB0, 256, 0, stream>>>(deg0, N_NODES);
    scan_blk<<<NB0, 256, 0, stream>>>(cnt0, offs0, bsum, N_NODES);
    scan_top<<<1, 512, 0, stream>>>(bsum, NB0);
    scan_add<<<NB0, 256, 0, stream>>>(offs0, bsum, fill0, N_NODES);
    place_pack<<<NBE, 256, 0, stream>>>(ei1, ei0, edge_attr, deg0, fill0, pack0, N_EDGES);
    gather0<<<(N_NODES * 64) / 256, 256, 0, stream>>>(h16, x, deg0, offs0, cnt0, pack0, agg0);

    // ---- pool1 via cluster0 member lists ----
    fill_i32<<<NBC, 256, 0, stream>>>(cntc, NPOOL0, 0);
    seg_count<<<NB0, 256, 0, stream>>>(c0, cntc, N_NODES);
    scan_blk<<<NBC, 256, 0, stream>>>(cntc, offsc, bsum, NPOOL0);
    scan_top<<<1, 512, 0, stream>>>(bsum, NBC);
    scan_add<<<NBC, 256, 0, stream>>>(offsc, bsum, fillc, NPOOL0);
    place_idx<<<NB0, 256, 0, stream>>>(c0, fillc, listc, N_NODES);
    fill_i32<<<NBC, 256, 0, stream>>>(pb, NPOOL0, 0);
    segmax_i32<<<NB0, 256, 0, stream>>>(c0, batch, pb, N_NODES);
    pool1_gather<<<(NPOOL0 * 64) / 256, 256, 0, stream>>>(agg0, x, offsc, cntc, listc, h2);

    // ---- pool2 via cluster1 member lists ----
    fill_i32<<<NB1, 256, 0, stream>>>(cntd, NPOOL1, 0);
    seg_count<<<NBC, 256, 0, stream>>>(c1, cntd, NPOOL0);
    scan_blk<<<NB1, 256, 0, stream>>>(cntd, offsd, bsum, NPOOL1);
    scan_top<<<1, 512, 0, stream>>>(bsum, NB1);
    scan_add<<<NB1, 256, 0, stream>>>(offsd, bsum, filld, NPOOL1);
    place_idx<<<NBC, 256, 0, stream>>>(c1, filld, listd, NPOOL0);
    fill_i32<<<NB1, 256, 0, stream>>>(pb2, NPOOL1, 0);
    segmax_i32<<<NBC, 256, 0, stream>>>(c1, pb, pb2, NPOOL0);
    pool2_gather<<<(NPOOL1 * 64) / 256, 256, 0, stream>>>(h2, offsd, cntd, listd, x2);

    // ---- mpnn2: edge remap + MFMA MLP + CSR(pack) + gather ----
    fill_f32<<<NB1, 256, 0, stream>>>(deg2, NPOOL1, 1.0f);
    fill_i32<<<NB1, 256, 0, stream>>>(cnt2, NPOOL1, 0);
    edgemap<<<NBE, 256, 0, stream>>>(ei0, ei1, c0, c1, src2, dst2, deg2, cnt2, N_EDGES);
    rsqrt_ip<<<NB1, 256, 0, stream>>>(deg2, NPOOL1);
    scan_blk<<<NB1, 256, 0, stream>>>(cnt2, offs2, bsum, NPOOL1);
    scan_top<<<1, 512, 0, stream>>>(bsum, NB1);
    scan_add<<<NB1, 256, 0, stream>>>(offs2, bsum, fill2, NPOOL1);
    mlp_mfma<128, 256, true><<<(NPOOL1 + 63) / 64, 256, 0, stream>>>(
        x2, NPOOL1, w2a16, b2a, g2, be2, w2b16, b2b, hm2);
    place_pack<<<NBE, 256, 0, stream>>>(dst2, src2, edge_attr, deg2, fill2, pack2, N_EDGES);
    gather2<<<(NPOOL1 * 64) / 256, 256, 0, stream>>>(hm2, deg2, offs2, cnt2, pack2, agg2);

    // ---- graph buckets + fused gpool/head ----
    fill_i32<<<1, 256, 0, stream>>>(cntg, NGRAPH, 0);
    seg_count<<<NB1, 256, 0, stream>>>(pb2, cntg, NPOOL1);
    scan_blk<<<1, 256, 0, stream>>>(cntg, offsg, bsum, NGRAPH);
    scan_top<<<1, 512, 0, stream>>>(bsum, 1);
    scan_add<<<1, 256, 0, stream>>>(offsg, bsum, fillg, NGRAPH);
    place_idx<<<NB1, 256, 0, stream>>>(pb2, fillg, listg, NPOOL1);
    head_fused<<<NGRAPH, 128, 0, stream>>>(agg2, offsg, cntg, listg, energy,
                                           emb_w, emb_b, emb_g, emb_be,
                                           lw1, lb1, lg, lbe, lw2, lb2, out);
}

// Round 6
// 1218.752 us; speedup vs baseline: 1.6494x; 1.6494x over previous
//
#include <hip/hip_runtime.h>
#include <math.h>

#define N_NODES 100000
#define N_EDGES 1600000
#define DIM     128
#define NPOOL0  50000
#define NPOOL1  25000
#define NGRAPH  64

typedef __attribute__((ext_vector_type(8))) short short8;
typedef __attribute__((ext_vector_type(4))) float f32x4;

__device__ __forceinline__ float lrelu(float v) { return v > 0.f ? v : 0.01f * v; }

// f32 -> bf16 round-to-nearest-even
__device__ __forceinline__ unsigned short f2bf(float f) {
    unsigned u = __float_as_uint(f);
    unsigned r = u + 0x7FFFu + ((u >> 16) & 1u);
    return (unsigned short)(r >> 16);
}

// float atomic max: signed-max for v>=0, unsigned-min for v<0 (monotone, -inf init; verified r1..r5)
__device__ __forceinline__ void atomicMaxF(float* addr, float val) {
    if (val >= 0.f) atomicMax((int*)addr, __float_as_int(val));
    else            atomicMin((unsigned int*)addr, __float_as_uint(val));
}

// ---------------- fills ----------------
__global__ __launch_bounds__(256) void fill_f32(float* __restrict__ p, int n, float v) {
    int i = blockIdx.x * 256 + threadIdx.x;
    if (i < n) p[i] = v;
}
__global__ __launch_bounds__(256) void fill_i32(int* __restrict__ p, int n, int v) {
    int i = blockIdx.x * 256 + threadIdx.x;
    if (i < n) p[i] = v;
}
__global__ __launch_bounds__(256) void conv_bf16(const float* __restrict__ in, unsigned short* __restrict__ out, int n) {
    int i = blockIdx.x * 256 + threadIdx.x;
    if (i < n) out[i] = f2bf(in[i]);
}

// ---------------- MFMA 2-layer MLP ----------------
template<int KIN, int HID, bool BF16IN>
__global__ __launch_bounds__(256) void mlp_mfma(
        const void* __restrict__ Xv, int R,
        const unsigned short* __restrict__ W1, const float* __restrict__ B1,
        const float* __restrict__ G1, const float* __restrict__ BE1,
        const unsigned short* __restrict__ W2, const float* __restrict__ B2,
        unsigned short* __restrict__ Y)
{
    constexpr int XS_S = KIN + 8;
    constexpr int TS_S = HID + 8;
    __shared__ unsigned short xs[64 * XS_S];
    __shared__ unsigned short ts[64 * TS_S];

    const int tid = threadIdx.x;
    const int r0 = blockIdx.x * 64;

    {
        const int row = tid >> 2;
        const int c0 = (tid & 3) * 32;
        const int gr = r0 + row;
        if (BF16IN) {
            const unsigned short* X = (const unsigned short*)Xv;
            #pragma unroll
            for (int q = 0; q < 4; ++q) {
                short8 v = short8{0,0,0,0,0,0,0,0};
                if (gr < R) v = *(const short8*)&X[(size_t)gr * KIN + c0 + q * 8];
                *(short8*)&xs[row * XS_S + c0 + q * 8] = v;
            }
        } else {
            const float* X = (const float*)Xv;
            #pragma unroll
            for (int q = 0; q < 4; ++q) {
                short8 v = short8{0,0,0,0,0,0,0,0};
                if (gr < R) {
                    float4 a = *(const float4*)&X[(size_t)gr * KIN + c0 + q * 8];
                    float4 b = *(const float4*)&X[(size_t)gr * KIN + c0 + q * 8 + 4];
                    v[0] = (short)f2bf(a.x); v[1] = (short)f2bf(a.y);
                    v[2] = (short)f2bf(a.z); v[3] = (short)f2bf(a.w);
                    v[4] = (short)f2bf(b.x); v[5] = (short)f2bf(b.y);
                    v[6] = (short)f2bf(b.z); v[7] = (short)f2bf(b.w);
                }
                *(short8*)&xs[row * XS_S + c0 + q * 8] = v;
            }
        }
    }
    __syncthreads();

    const int wv = tid >> 6;
    const int lane = tid & 63;
    const int lr = lane & 15;
    const int lq = lane >> 4;
    const int arow = wv * 16 + lr;

    constexpr int NCG1 = HID / 16;
    constexpr int NK1 = KIN / 32;
    f32x4 acc1[NCG1] = {};
    for (int kc = 0; kc < NK1; ++kc) {
        short8 a = *(short8*)&xs[arow * XS_S + kc * 32 + lq * 8];
        #pragma unroll
        for (int cg = 0; cg < NCG1; ++cg) {
            short8 b = *(const short8*)&W1[(size_t)(cg * 16 + lr) * KIN + kc * 32 + lq * 8];
            acc1[cg] = __builtin_amdgcn_mfma_f32_16x16x32_bf16(a, b, acc1[cg], 0, 0, 0);
        }
    }
    #pragma unroll
    for (int cg = 0; cg < NCG1; ++cg) {
        const int c = cg * 16 + lr;
        const float bb = B1[c], gg = G1[c], ee = BE1[c];
        #pragma unroll
        for (int q = 0; q < 4; ++q) {
            const int rr = wv * 16 + lq * 4 + q;
            float v = (acc1[cg][q] + bb) * gg + ee;
            ts[rr * TS_S + c] = f2bf(lrelu(v));
        }
    }

    constexpr int NK2 = HID / 32;
    f32x4 acc2[8] = {};
    for (int kc = 0; kc < NK2; ++kc) {
        short8 a = *(short8*)&ts[arow * TS_S + kc * 32 + lq * 8];
        #pragma unroll
        for (int cg = 0; cg < 8; ++cg) {
            short8 b = *(const short8*)&W2[(size_t)(cg * 16 + lr) * HID + kc * 32 + lq * 8];
            acc2[cg] = __builtin_amdgcn_mfma_f32_16x16x32_bf16(a, b, acc2[cg], 0, 0, 0);
        }
    }
    #pragma unroll
    for (int cg = 0; cg < 8; ++cg) {
        const int c = cg * 16 + lr;
        const float bb = B2[c];
        #pragma unroll
        for (int q = 0; q < 4; ++q) {
            const int gr = r0 + wv * 16 + lq * 4 + q;
            if (gr < R) Y[(size_t)gr * 128 + c] = f2bf(acc2[cg][q] + bb);
        }
    }
}

// ---------------- CSR build ----------------
__global__ __launch_bounds__(256) void count0(const int* __restrict__ src, const int* __restrict__ dst,
                                              float* __restrict__ deg, int* __restrict__ cnt, int E) {
    int e = blockIdx.x * 256 + threadIdx.x;
    if (e < E) {
        atomicAdd(&deg[src[e]], 1.0f);
        atomicAdd(&cnt[dst[e]], 1);
    }
}
__global__ __launch_bounds__(256) void rsqrt_ip(float* __restrict__ p, int n) {
    int i = blockIdx.x * 256 + threadIdx.x;
    if (i < n) p[i] = rsqrtf(p[i]);
}
__global__ __launch_bounds__(256) void scan_blk(const int* __restrict__ cnt, int* __restrict__ offs,
                                                int* __restrict__ bsum, int n) {
    __shared__ int s[256];
    const int tid = threadIdx.x;
    const int i = blockIdx.x * 256 + tid;
    int v = (i < n) ? cnt[i] : 0;
    s[tid] = v;
    __syncthreads();
    #pragma unroll
    for (int d = 1; d < 256; d <<= 1) {
        int t = (tid >= d) ? s[tid - d] : 0;
        __syncthreads();
        s[tid] += t;
        __syncthreads();
    }
    if (i < n) offs[i] = s[tid] - v;
    if (tid == 255) bsum[blockIdx.x] = s[255];
}
__global__ __launch_bounds__(512) void scan_top(int* __restrict__ bsum, int nb) {
    __shared__ int s[512];
    const int tid = threadIdx.x;
    int v = (tid < nb) ? bsum[tid] : 0;
    s[tid] = v;
    __syncthreads();
    #pragma unroll
    for (int d = 1; d < 512; d <<= 1) {
        int t = (tid >= d) ? s[tid - d] : 0;
        __syncthreads();
        s[tid] += t;
        __syncthreads();
    }
    if (tid < nb) bsum[tid] = s[tid] - v;
}
__global__ __launch_bounds__(256) void scan_add(int* __restrict__ offs, const int* __restrict__ bsum,
                                                int* __restrict__ fill, int n) {
    int i = blockIdx.x * 256 + threadIdx.x;
    if (i < n) {
        int o = offs[i] + bsum[i >> 8];
        offs[i] = o;
        fill[i] = o;
    }
}
__global__ __launch_bounds__(256) void place_pack(const int* __restrict__ dst, const int* __restrict__ srcA,
                                                  const float* __restrict__ ea, const float* __restrict__ dis,
                                                  int* __restrict__ fill, int2* __restrict__ pack, int E) {
    int e = blockIdx.x * 256 + threadIdx.x;
    if (e < E) {
        int d = dst[e];
        int s = srcA[e];
        int pos = atomicAdd(&fill[d], 1);
        pack[pos] = make_int2(s, __float_as_int(dis[s] * ea[e]));
    }
}
__global__ __launch_bounds__(256) void edgemap(
        const int* __restrict__ ei0, const int* __restrict__ ei1,
        const int* __restrict__ c0, const int* __restrict__ c1,
        int* __restrict__ src2, int* __restrict__ dst2,
        float* __restrict__ deg2, int* __restrict__ cnt2, int E)
{
    int e = blockIdx.x * 256 + threadIdx.x;
    if (e < E) {
        int s = c1[c0[ei0[e]]];
        int d = c1[c0[ei1[e]]];
        src2[e] = s;
        dst2[e] = d;
        atomicAdd(&deg2[s], 1.0f);
        atomicAdd(&cnt2[d], 1);
    }
}
__global__ __launch_bounds__(256) void seg_count(const int* __restrict__ map, int* __restrict__ cnt, int n) {
    int i = blockIdx.x * 256 + threadIdx.x;
    if (i < n) atomicAdd(&cnt[map[i]], 1);
}
__global__ __launch_bounds__(256) void place_idx(const int* __restrict__ map, int* __restrict__ fill,
                                                 int* __restrict__ list, int n) {
    int i = blockIdx.x * 256 + threadIdx.x;
    if (i < n) {
        int pos = atomicAdd(&fill[map[i]], 1);
        list[pos] = i;
    }
}
__global__ __launch_bounds__(256) void segmax_i32(const int* __restrict__ map, const int* __restrict__ vals,
                                                  int* __restrict__ out, int n) {
    int i = blockIdx.x * 256 + threadIdx.x;
    if (i < n) atomicMax(&out[map[i]], vals[i]);
}

// ---------------- gather-reduce (one wave per dst node; packed CSR; readlane broadcast) ----------------
#define EDGE_ITER(K, A0, A1) {                                                  \
    int s_ = __builtin_amdgcn_readlane(pv.x, (K));                              \
    float w_ = __int_as_float(__builtin_amdgcn_readlane(pv.y, (K)));            \
    unsigned hv_ = hrows[(size_t)s_ * 64 + lane];                               \
    float c_ = w_ * di;                                                         \
    A0 += c_ * __uint_as_float(hv_ << 16);                                      \
    A1 += c_ * __uint_as_float(hv_ & 0xFFFF0000u); }

// mpnn0 + residual: agg0[i] = bf16( dis^2*h[i] + sum + x[i] )
__global__ __launch_bounds__(256) void gather0(
        const unsigned short* __restrict__ h16, const float* __restrict__ x,
        const float* __restrict__ dis, const int* __restrict__ offs,
        const int* __restrict__ cnt, const int2* __restrict__ pack,
        unsigned* __restrict__ agg0)
{
    const int wid = (blockIdx.x * 256 + threadIdx.x) >> 6;
    if (wid >= N_NODES) return;
    const int lane = threadIdx.x & 63;
    const float di = dis[wid];
    const unsigned* hrows = (const unsigned*)h16;

    unsigned hself = hrows[(size_t)wid * 64 + lane];
    float a0 = di * di * __uint_as_float(hself << 16);
    float a1 = di * di * __uint_as_float(hself & 0xFFFF0000u);
    float b0 = 0.f, b1 = 0.f;

    const int base = offs[wid], n = cnt[wid];
    int k0 = 0;
    for (; k0 + 64 <= n; k0 += 64) {
        int2 pv = pack[base + k0 + lane];
        #pragma unroll
        for (int k = 0; k < 64; k += 2) {
            EDGE_ITER(k,     a0, a1);
            EDGE_ITER(k + 1, b0, b1);
        }
    }
    const int rem = n - k0;
    if (rem > 0) {
        int2 pv = (lane < rem) ? pack[base + k0 + lane] : make_int2(0, 0);
        #pragma unroll 4
        for (int k = 0; k < rem; ++k) EDGE_ITER(k, a0, a1);
    }
    a0 += b0; a1 += b1;

    float2 xv = *(const float2*)&x[(size_t)wid * DIM + lane * 2];
    agg0[(size_t)wid * 64 + lane] =
        ((unsigned)f2bf(a1 + xv.y) << 16) | (unsigned)f2bf(a0 + xv.x);
}

// mpnn2: agg2[i] = lrelu( dis^2*hm2[i] + sum )  (f32 row stores)
__global__ __launch_bounds__(256) void gather2(
        const unsigned short* __restrict__ hm2,
        const float* __restrict__ dis, const int* __restrict__ offs,
        const int* __restrict__ cnt, const int2* __restrict__ pack,
        float* __restrict__ agg2)
{
    const int wid = (blockIdx.x * 256 + threadIdx.x) >> 6;
    if (wid >= NPOOL1) return;
    const int lane = threadIdx.x & 63;
    const float di = dis[wid];
    const unsigned* hrows = (const unsigned*)hm2;

    unsigned hself = hrows[(size_t)wid * 64 + lane];
    float a0 = di * di * __uint_as_float(hself << 16);
    float a1 = di * di * __uint_as_float(hself & 0xFFFF0000u);
    float b0 = 0.f, b1 = 0.f;

    const int base = offs[wid], n = cnt[wid];
    int k0 = 0;
    for (; k0 + 64 <= n; k0 += 64) {
        int2 pv = pack[base + k0 + lane];
        #pragma unroll
        for (int k = 0; k < 64; k += 2) {
            EDGE_ITER(k,     a0, a1);
            EDGE_ITER(k + 1, b0, b1);
        }
    }
    const int rem = n - k0;
    if (rem > 0) {
        int2 pv = (lane < rem) ? pack[base + k0 + lane] : make_int2(0, 0);
        #pragma unroll 4
        for (int k = 0; k < rem; ++k) EDGE_ITER(k, a0, a1);
    }
    a0 += b0; a1 += b1;

    float2 o = make_float2(lrelu(a0), lrelu(a1));
    *(float2*)&agg2[(size_t)wid * DIM + lane * 2] = o;
}

// ---------------- pool gathers (atomic-free segment max via member lists) ----------------
__global__ __launch_bounds__(256) void pool1_gather(
        const unsigned* __restrict__ agg0, const float* __restrict__ x,
        const int* __restrict__ offsc, const int* __restrict__ cntc,
        const int* __restrict__ listc, unsigned* __restrict__ h2)
{
    const int c = (blockIdx.x * 256 + threadIdx.x) >> 6;
    if (c >= NPOOL0) return;
    const int lane = threadIdx.x & 63;
    const int base = offsc[c], n = cntc[c];
    float p0 = -INFINITY, p1 = -INFINITY, o0 = -INFINITY, o1 = -INFINITY;
    for (int k = 0; k < n; ++k) {
        const int node = listc[base + k];
        const unsigned hv = agg0[(size_t)node * 64 + lane];
        const float2 xv = *(const float2*)&x[(size_t)node * 128 + lane * 2];
        p0 = fmaxf(p0, lrelu(__uint_as_float(hv << 16)));
        p1 = fmaxf(p1, lrelu(__uint_as_float(hv & 0xFFFF0000u)));
        o0 = fmaxf(o0, xv.x);
        o1 = fmaxf(o1, xv.y);
    }
    p0 = (p0 == -INFINITY) ? 0.f : p0;
    p1 = (p1 == -INFINITY) ? 0.f : p1;
    o0 = (o0 == -INFINITY) ? 0.f : o0;
    o1 = (o1 == -INFINITY) ? 0.f : o1;
    h2[(size_t)c * 64 + lane] =
        ((unsigned)f2bf(p1 + o1) << 16) | (unsigned)f2bf(p0 + o0);
}

__global__ __launch_bounds__(256) void pool2_gather(
        const unsigned* __restrict__ h2,
        const int* __restrict__ offsd, const int* __restrict__ cntd,
        const int* __restrict__ listd, unsigned* __restrict__ x2)
{
    const int d = (blockIdx.x * 256 + threadIdx.x) >> 6;
    if (d >= NPOOL1) return;
    const int lane = threadIdx.x & 63;
    const int base = offsd[d], n = cntd[d];
    float m0 = -INFINITY, m1 = -INFINITY;
    for (int k = 0; k < n; ++k) {
        const int node = listd[base + k];
        const unsigned hv = h2[(size_t)node * 64 + lane];
        m0 = fmaxf(m0, lrelu(__uint_as_float(hv << 16)));
        m1 = fmaxf(m1, lrelu(__uint_as_float(hv & 0xFFFF0000u)));
    }
    m0 = (m0 == -INFINITY) ? 0.f : m0;
    m1 = (m1 == -INFINITY) ? 0.f : m1;
    x2[(size_t)d * 64 + lane] = ((unsigned)f2bf(m1) << 16) | (unsigned)f2bf(m0);
}

// ---------------- parallel global max pool over graph-sorted list ----------------
// 512 waves; wave owns a contiguous 49-slice of listg; register running max,
// flushed to gmax via atomicMaxF only on graph-boundary crossings (~64+511 flushes).
__global__ __launch_bounds__(256) void gpool_scan(
        const float* __restrict__ agg2, const int* __restrict__ listg,
        const int* __restrict__ pb2, float* __restrict__ gmax)
{
    const int wave = (blockIdx.x * 256 + threadIdx.x) >> 6;   // 0..511
    const int lane = threadIdx.x & 63;
    const int CH = (NPOOL1 + 511) / 512;                      // 49
    const int p0 = wave * CH;
    const int p1 = min(p0 + CH, NPOOL1);
    if (p0 >= NPOOL1) return;

    float m0 = -INFINITY, m1 = -INFINITY;
    int cur = -1;
    for (int p = p0; p < p1; ++p) {
        const int node = listg[p];
        const int g = pb2[node];                              // wave-uniform
        if (g != cur) {
            if (cur >= 0) {
                float* gp = &gmax[(size_t)cur * DIM + lane * 2];
                atomicMaxF(gp + 0, m0);
                atomicMaxF(gp + 1, m1);
            }
            cur = g; m0 = -INFINITY; m1 = -INFINITY;
        }
        const float2 v = *(const float2*)&agg2[(size_t)node * DIM + lane * 2];
        m0 = fmaxf(m0, v.x);
        m1 = fmaxf(m1, v.y);
    }
    float* gp = &gmax[(size_t)cur * DIM + lane * 2];
    atomicMaxF(gp + 0, m0);
    atomicMaxF(gp + 1, m1);
}

// ---------------- head ----------------
__global__ __launch_bounds__(128) void head(
        const float* __restrict__ gmax, const float* __restrict__ energy,
        const float* __restrict__ emb_w, const float* __restrict__ emb_b,
        const float* __restrict__ emb_g, const float* __restrict__ emb_be,
        const float* __restrict__ lw1, const float* __restrict__ lb1,
        const float* __restrict__ lg, const float* __restrict__ lbe,
        const float* __restrict__ lw2, const float* __restrict__ lb2,
        float* __restrict__ out)
{
    const int g = blockIdx.x;
    const int t = threadIdx.x;
    __shared__ float z[136];
    __shared__ float red[128];

    {
        float v = gmax[(size_t)g * DIM + t];
        z[t] = (v == -INFINITY) ? 0.f : v;
    }
    if (t < 8) {
        float s = 0.f;
        #pragma unroll
        for (int k = 0; k < 21; ++k) s += energy[g * 21 + k] * emb_w[t * 21 + k];
        s = (s + emb_b[t]) * emb_g[t] + emb_be[t];
        z[128 + t] = lrelu(s);
    }
    __syncthreads();
    float s = 0.f;
    #pragma unroll 8
    for (int k = 0; k < 136; ++k) s += z[k] * lw1[t * 136 + k];
    float z2 = lrelu((s + lb1[t]) * lg[t] + lbe[t]);
    red[t] = z2 * lw2[t];
    __syncthreads();
    if (t == 0) {
        float acc = lb2[0];
        for (int k = 0; k < 128; ++k) acc += red[k];
        out[g] = acc;
    }
}

extern "C" void kernel_launch(void* const* d_in, const int* in_sizes, int n_in,
                              void* d_out, int out_size, void* d_ws, size_t ws_size,
                              hipStream_t stream) {
    const float* x        = (const float*)d_in[0];
    const float* edge_attr= (const float*)d_in[1];
    const float* energy   = (const float*)d_in[2];
    const float* w0a = (const float*)d_in[3];
    const float* b0a = (const float*)d_in[4];
    const float* g0  = (const float*)d_in[5];
    const float* be0 = (const float*)d_in[6];
    const float* w0b = (const float*)d_in[7];
    const float* b0b = (const float*)d_in[8];
    const float* w2a = (const float*)d_in[15];
    const float* b2a = (const float*)d_in[16];
    const float* g2  = (const float*)d_in[17];
    const float* be2 = (const float*)d_in[18];
    const float* w2b = (const float*)d_in[19];
    const float* b2b = (const float*)d_in[20];
    const float* emb_w  = (const float*)d_in[21];
    const float* emb_b  = (const float*)d_in[22];
    const float* emb_g  = (const float*)d_in[23];
    const float* emb_be = (const float*)d_in[24];
    const float* lw1 = (const float*)d_in[25];
    const float* lb1 = (const float*)d_in[26];
    const float* lg  = (const float*)d_in[27];
    const float* lbe = (const float*)d_in[28];
    const float* lw2 = (const float*)d_in[29];
    const float* lb2 = (const float*)d_in[30];
    const int* ei0   = (const int*)d_in[31];
    const int* ei1   = ei0 + N_EDGES;
    const int* batch = (const int*)d_in[32];
    const int* c0    = (const int*)d_in[33];
    const int* c1    = (const int*)d_in[34];
    float* out = (float*)d_out;

    // ---- workspace layout (peak ~87.4 MB) ----
    char* ws = (char*)d_ws;
    unsigned short* h16 = (unsigned short*)(ws + 0);         // [N,128] bf16 (dead after gather0)
    int*   src2  = (int*)(ws + 0);                           // [E] (alias h16)
    int*   dst2  = (int*)(ws + 6400000);                     // [E]
    float* agg2  = (float*)(ws + 12800000);                  // [N1,128] f32
    unsigned* agg0 = (unsigned*)(ws + 25600000);             // [N,128] bf16 (dead after pool1_gather)
    unsigned short* hm2 = (unsigned short*)(ws + 25600000);  // [N1,128] bf16 (alias agg0)
    int2*  pack0 = (int2*)(ws + 51200000);                   // [E]
    int2*  pack2 = (int2*)(ws + 51200000);                   // alias
    unsigned* h2 = (unsigned*)(ws + 64000000);               // [N0,128] bf16
    unsigned* x2 = (unsigned*)(ws + 76800000);               // [N1,128] bf16
    float* deg0  = (float*)(ws + 83200000);
    int*   cnt0  = (int*)(ws + 83600000);
    int*   offs0 = (int*)(ws + 84000000);
    int*   fill0 = (int*)(ws + 84400000);
    int*   cntc  = (int*)(ws + 84800000);
    int*   offsc = (int*)(ws + 85000000);
    int*   fillc = (int*)(ws + 85200000);
    int*   listc = (int*)(ws + 85400000);                    // [N]
    int*   pb    = (int*)(ws + 85800000);
    int*   pb2   = (int*)(ws + 86000000);
    int*   cntd  = (int*)(ws + 86100000);
    int*   offsd = (int*)(ws + 86200000);
    int*   filld = (int*)(ws + 86300000);
    int*   listd = (int*)(ws + 86400000);                    // [N0]
    float* deg2  = (float*)(ws + 86600000);
    int*   cnt2  = (int*)(ws + 86700000);
    int*   offs2 = (int*)(ws + 86800000);
    int*   fill2 = (int*)(ws + 86900000);
    int*   cntg  = (int*)(ws + 87000000);                    // [64]
    int*   offsg = (int*)(ws + 87000256);
    int*   fillg = (int*)(ws + 87000512);
    int*   listg = (int*)(ws + 87001088);                    // [N1]
    int*   bsum  = (int*)(ws + 87102096);                    // [<=512]
    unsigned short* w0a16 = (unsigned short*)(ws + 87105000);
    unsigned short* w0b16 = (unsigned short*)(ws + 87138000);
    unsigned short* w2a16 = (unsigned short*)(ws + 87171000);
    unsigned short* w2b16 = (unsigned short*)(ws + 87237000);
    float* gmax  = (float*)(ws + 87303000);                  // [64,128] f32

    (void)in_sizes; (void)n_in; (void)out_size; (void)ws_size;

    const int NB0 = (N_NODES + 255) / 256;   // 391
    const int NBC = (NPOOL0 + 255) / 256;    // 196
    const int NB1 = (NPOOL1 + 255) / 256;    // 98
    const int NBE = (N_EDGES + 255) / 256;

    // ---- weight conversion (bf16) ----
    conv_bf16<<<64, 256, 0, stream>>>(w0a, w0a16, 16384);
    conv_bf16<<<64, 256, 0, stream>>>(w0b, w0b16, 16384);
    conv_bf16<<<128, 256, 0, stream>>>(w2a, w2a16, 32768);
    conv_bf16<<<128, 256, 0, stream>>>(w2b, w2b16, 32768);

    // ---- mpnn0: MFMA MLP + CSR(pack) + gather ----
    fill_f32<<<NB0, 256, 0, stream>>>(deg0, N_NODES, 1.0f);
    fill_i32<<<NB0, 256, 0, stream>>>(cnt0, N_NODES, 0);
    mlp_mfma<128, 128, false><<<(N_NODES + 63) / 64, 256, 0, stream>>>(
        x, N_NODES, w0a16, b0a, g0, be0, w0b16, b0b, h16);
    count0<<<NBE, 256, 0, stream>>>(ei0, ei1, deg0, cnt0, N_EDGES);
    rsqrt_ip<<<NB0, 256, 0, stream>>>(deg0, N_NODES);
    scan_blk<<<NB0, 256, 0, stream>>>(cnt0, offs0, bsum, N_NODES);
    scan_top<<<1, 512, 0, stream>>>(bsum, NB0);
    scan_add<<<NB0, 256, 0, stream>>>(offs0, bsum, fill0, N_NODES);
    place_pack<<<NBE, 256, 0, stream>>>(ei1, ei0, edge_attr, deg0, fill0, pack0, N_EDGES);
    gather0<<<(N_NODES * 64) / 256, 256, 0, stream>>>(h16, x, deg0, offs0, cnt0, pack0, agg0);

    // ---- pool1 via cluster0 member lists ----
    fill_i32<<<NBC, 256, 0, stream>>>(cntc, NPOOL0, 0);
    seg_count<<<NB0, 256, 0, stream>>>(c0, cntc, N_NODES);
    scan_blk<<<NBC, 256, 0, stream>>>(cntc, offsc, bsum, NPOOL0);
    scan_top<<<1, 512, 0, stream>>>(bsum, NBC);
    scan_add<<<NBC, 256, 0, stream>>>(offsc, bsum, fillc, NPOOL0);
    place_idx<<<NB0, 256, 0, stream>>>(c0, fillc, listc, N_NODES);
    fill_i32<<<NBC, 256, 0, stream>>>(pb, NPOOL0, 0);
    segmax_i32<<<NB0, 256, 0, stream>>>(c0, batch, pb, N_NODES);
    pool1_gather<<<(NPOOL0 * 64) / 256, 256, 0, stream>>>(agg0, x, offsc, cntc, listc, h2);

    // ---- pool2 via cluster1 member lists ----
    fill_i32<<<NB1, 256, 0, stream>>>(cntd, NPOOL1, 0);
    seg_count<<<NBC, 256, 0, stream>>>(c1, cntd, NPOOL0);
    scan_blk<<<NB1, 256, 0, stream>>>(cntd, offsd, bsum, NPOOL1);
    scan_top<<<1, 512, 0, stream>>>(bsum, NB1);
    scan_add<<<NB1, 256, 0, stream>>>(offsd, bsum, filld, NPOOL1);
    place_idx<<<NBC, 256, 0, stream>>>(c1, filld, listd, NPOOL0);
    fill_i32<<<NB1, 256, 0, stream>>>(pb2, NPOOL1, 0);
    segmax_i32<<<NBC, 256, 0, stream>>>(c1, pb, pb2, NPOOL0);
    pool2_gather<<<(NPOOL1 * 64) / 256, 256, 0, stream>>>(h2, offsd, cntd, listd, x2);

    // ---- mpnn2: edge remap + MFMA MLP + CSR(pack) + gather ----
    fill_f32<<<NB1, 256, 0, stream>>>(deg2, NPOOL1, 1.0f);
    fill_i32<<<NB1, 256, 0, stream>>>(cnt2, NPOOL1, 0);
    edgemap<<<NBE, 256, 0, stream>>>(ei0, ei1, c0, c1, src2, dst2, deg2, cnt2, N_EDGES);
    rsqrt_ip<<<NB1, 256, 0, stream>>>(deg2, NPOOL1);
    scan_blk<<<NB1, 256, 0, stream>>>(cnt2, offs2, bsum, NPOOL1);
    scan_top<<<1, 512, 0, stream>>>(bsum, NB1);
    scan_add<<<NB1, 256, 0, stream>>>(offs2, bsum, fill2, NPOOL1);
    mlp_mfma<128, 256, true><<<(NPOOL1 + 63) / 64, 256, 0, stream>>>(
        x2, NPOOL1, w2a16, b2a, g2, be2, w2b16, b2b, hm2);
    place_pack<<<NBE, 256, 0, stream>>>(dst2, src2, edge_attr, deg2, fill2, pack2, N_EDGES);
    gather2<<<(NPOOL1 * 64) / 256, 256, 0, stream>>>(hm2, deg2, offs2, cnt2, pack2, agg2);

    // ---- graph buckets + parallel gpool + head ----
    fill_i32<<<1, 256, 0, stream>>>(cntg, NGRAPH, 0);
    seg_count<<<NB1, 256, 0, stream>>>(pb2, cntg, NPOOL1);
    scan_blk<<<1, 256, 0, stream>>>(cntg, offsg, bsum, NGRAPH);
    scan_top<<<1, 512, 0, stream>>>(bsum, 1);
    scan_add<<<1, 256, 0, stream>>>(offsg, bsum, fillg, NGRAPH);
    place_idx<<<NB1, 256, 0, stream>>>(pb2, fillg, listg, NPOOL1);
    fill_f32<<<(NGRAPH * DIM + 255) / 256, 256, 0, stream>>>(gmax, NGRAPH * DIM, -INFINITY);
    gpool_scan<<<128, 256, 0, stream>>>(agg2, listg, pb2, gmax);
    head<<<NGRAPH, 128, 0, stream>>>(gmax, energy, emb_w, emb_b, emb_g, emb_be,
                                     lw1, lb1, lg, lbe, lw2, lb2, out);
}

// Round 7
// 1071.017 us; speedup vs baseline: 1.8769x; 1.1379x over previous
//
#include <hip/hip_runtime.h>
#include <math.h>

#define N_NODES 100000
#define N_EDGES 1600000
#define DIM     128
#define NPOOL0  50000
#define NPOOL1  25000
#define NGRAPH  64

typedef __attribute__((ext_vector_type(8))) short short8;
typedef __attribute__((ext_vector_type(4))) float f32x4;

__device__ __forceinline__ float lrelu(float v) { return v > 0.f ? v : 0.01f * v; }

// f32 -> bf16 round-to-nearest-even
__device__ __forceinline__ unsigned short f2bf(float f) {
    unsigned u = __float_as_uint(f);
    unsigned r = u + 0x7FFFu + ((u >> 16) & 1u);
    return (unsigned short)(r >> 16);
}

// float atomic max: signed-max for v>=0, unsigned-min for v<0 (monotone, -inf init; verified r1..r6)
__device__ __forceinline__ void atomicMaxF(float* addr, float val) {
    if (val >= 0.f) atomicMax((int*)addr, __float_as_int(val));
    else            atomicMin((unsigned int*)addr, __float_as_uint(val));
}

// ---------------- consolidated init ----------------
__global__ __launch_bounds__(256) void init_f(float* __restrict__ deg0, float* __restrict__ deg2,
                                              float* __restrict__ gmax) {
    int i = blockIdx.x * 256 + threadIdx.x;
    if (i < N_NODES) deg0[i] = 1.0f;
    else if (i < N_NODES + NPOOL1) deg2[i - N_NODES] = 1.0f;
    else if (i < N_NODES + NPOOL1 + NGRAPH * DIM) gmax[i - N_NODES - NPOOL1] = -INFINITY;
}
__global__ __launch_bounds__(256) void conv_weights(
        const float* __restrict__ w0a, const float* __restrict__ w0b,
        const float* __restrict__ w2a, const float* __restrict__ w2b,
        unsigned short* __restrict__ o0a, unsigned short* __restrict__ o0b,
        unsigned short* __restrict__ o2a, unsigned short* __restrict__ o2b) {
    int i = blockIdx.x * 256 + threadIdx.x;   // 98304 total
    if (i < 16384) o0a[i] = f2bf(w0a[i]);
    else if (i < 32768) o0b[i - 16384] = f2bf(w0b[i - 16384]);
    else if (i < 65536) o2a[i - 32768] = f2bf(w2a[i - 32768]);
    else if (i < 98304) o2b[i - 65536] = f2bf(w2b[i - 65536]);
}

// ---------------- MFMA 2-layer MLP ----------------
template<int KIN, int HID, bool BF16IN>
__global__ __launch_bounds__(256) void mlp_mfma(
        const void* __restrict__ Xv, int R,
        const unsigned short* __restrict__ W1, const float* __restrict__ B1,
        const float* __restrict__ G1, const float* __restrict__ BE1,
        const unsigned short* __restrict__ W2, const float* __restrict__ B2,
        unsigned short* __restrict__ Y)
{
    constexpr int XS_S = KIN + 8;
    constexpr int TS_S = HID + 8;
    __shared__ unsigned short xs[64 * XS_S];
    __shared__ unsigned short ts[64 * TS_S];

    const int tid = threadIdx.x;
    const int r0 = blockIdx.x * 64;

    {
        const int row = tid >> 2;
        const int c0 = (tid & 3) * 32;
        const int gr = r0 + row;
        if (BF16IN) {
            const unsigned short* X = (const unsigned short*)Xv;
            #pragma unroll
            for (int q = 0; q < 4; ++q) {
                short8 v = short8{0,0,0,0,0,0,0,0};
                if (gr < R) v = *(const short8*)&X[(size_t)gr * KIN + c0 + q * 8];
                *(short8*)&xs[row * XS_S + c0 + q * 8] = v;
            }
        } else {
            const float* X = (const float*)Xv;
            #pragma unroll
            for (int q = 0; q < 4; ++q) {
                short8 v = short8{0,0,0,0,0,0,0,0};
                if (gr < R) {
                    float4 a = *(const float4*)&X[(size_t)gr * KIN + c0 + q * 8];
                    float4 b = *(const float4*)&X[(size_t)gr * KIN + c0 + q * 8 + 4];
                    v[0] = (short)f2bf(a.x); v[1] = (short)f2bf(a.y);
                    v[2] = (short)f2bf(a.z); v[3] = (short)f2bf(a.w);
                    v[4] = (short)f2bf(b.x); v[5] = (short)f2bf(b.y);
                    v[6] = (short)f2bf(b.z); v[7] = (short)f2bf(b.w);
                }
                *(short8*)&xs[row * XS_S + c0 + q * 8] = v;
            }
        }
    }
    __syncthreads();

    const int wv = tid >> 6;
    const int lane = tid & 63;
    const int lr = lane & 15;
    const int lq = lane >> 4;
    const int arow = wv * 16 + lr;

    constexpr int NCG1 = HID / 16;
    constexpr int NK1 = KIN / 32;
    f32x4 acc1[NCG1] = {};
    for (int kc = 0; kc < NK1; ++kc) {
        short8 a = *(short8*)&xs[arow * XS_S + kc * 32 + lq * 8];
        #pragma unroll
        for (int cg = 0; cg < NCG1; ++cg) {
            short8 b = *(const short8*)&W1[(size_t)(cg * 16 + lr) * KIN + kc * 32 + lq * 8];
            acc1[cg] = __builtin_amdgcn_mfma_f32_16x16x32_bf16(a, b, acc1[cg], 0, 0, 0);
        }
    }
    #pragma unroll
    for (int cg = 0; cg < NCG1; ++cg) {
        const int c = cg * 16 + lr;
        const float bb = B1[c], gg = G1[c], ee = BE1[c];
        #pragma unroll
        for (int q = 0; q < 4; ++q) {
            const int rr = wv * 16 + lq * 4 + q;
            float v = (acc1[cg][q] + bb) * gg + ee;
            ts[rr * TS_S + c] = f2bf(lrelu(v));
        }
    }

    constexpr int NK2 = HID / 32;
    f32x4 acc2[8] = {};
    for (int kc = 0; kc < NK2; ++kc) {
        short8 a = *(short8*)&ts[arow * TS_S + kc * 32 + lq * 8];
        #pragma unroll
        for (int cg = 0; cg < 8; ++cg) {
            short8 b = *(const short8*)&W2[(size_t)(cg * 16 + lr) * HID + kc * 32 + lq * 8];
            acc2[cg] = __builtin_amdgcn_mfma_f32_16x16x32_bf16(a, b, acc2[cg], 0, 0, 0);
        }
    }
    #pragma unroll
    for (int cg = 0; cg < 8; ++cg) {
        const int c = cg * 16 + lr;
        const float bb = B2[c];
        #pragma unroll
        for (int q = 0; q < 4; ++q) {
            const int gr = r0 + wv * 16 + lq * 4 + q;
            if (gr < R) Y[(size_t)gr * 128 + c] = f2bf(acc2[cg][q] + bb);
        }
    }
}

// ---------------- CSR build ----------------
__global__ __launch_bounds__(256) void count0(const int* __restrict__ src, const int* __restrict__ dst,
                                              float* __restrict__ deg, int* __restrict__ cnt, int E) {
    int e = blockIdx.x * 256 + threadIdx.x;
    if (e < E) {
        atomicAdd(&deg[src[e]], 1.0f);
        atomicAdd(&cnt[dst[e]], 1);
    }
}
__global__ __launch_bounds__(256) void rsqrt_ip(float* __restrict__ p, int n) {
    int i = blockIdx.x * 256 + threadIdx.x;
    if (i < n) p[i] = rsqrtf(p[i]);
}
// cmap[j]=c1[c0[j]]; deg2[m] += outdeg0(j); cnt2[m] += indeg0(j)
// (replaces 3.2M contended edge-atomics with 200K node-atomics — r6 post-mortem)
__global__ __launch_bounds__(256) void mapnode(
        const int* __restrict__ c0, const int* __restrict__ c1,
        const float* __restrict__ deg0, const int* __restrict__ cnt0,
        int* __restrict__ cmap, float* __restrict__ deg2, int* __restrict__ cnt2, int n) {
    int i = blockIdx.x * 256 + threadIdx.x;
    if (i < n) {
        int m = c1[c0[i]];
        cmap[i] = m;
        float oc = deg0[i] - 1.0f;
        if (oc != 0.f) atomicAdd(&deg2[m], oc);
        int ic = cnt0[i];
        if (ic) atomicAdd(&cnt2[m], ic);
    }
}
__global__ __launch_bounds__(256) void scan_blk(const int* __restrict__ cnt, int* __restrict__ offs,
                                                int* __restrict__ bsum, int n) {
    __shared__ int s[256];
    const int tid = threadIdx.x;
    const int i = blockIdx.x * 256 + tid;
    int v = (i < n) ? cnt[i] : 0;
    s[tid] = v;
    __syncthreads();
    #pragma unroll
    for (int d = 1; d < 256; d <<= 1) {
        int t = (tid >= d) ? s[tid - d] : 0;
        __syncthreads();
        s[tid] += t;
        __syncthreads();
    }
    if (i < n) offs[i] = s[tid] - v;
    if (tid == 255) bsum[blockIdx.x] = s[255];
}
__global__ __launch_bounds__(512) void scan_top(int* __restrict__ bsum, int nb) {
    __shared__ int s[512];
    const int tid = threadIdx.x;
    int v = (tid < nb) ? bsum[tid] : 0;
    s[tid] = v;
    __syncthreads();
    #pragma unroll
    for (int d = 1; d < 512; d <<= 1) {
        int t = (tid >= d) ? s[tid - d] : 0;
        __syncthreads();
        s[tid] += t;
        __syncthreads();
    }
    if (tid < nb) bsum[tid] = s[tid] - v;
}
__global__ __launch_bounds__(256) void scan_add(int* __restrict__ offs, const int* __restrict__ bsum,
                                                int* __restrict__ fill, int n) {
    int i = blockIdx.x * 256 + threadIdx.x;
    if (i < n) {
        int o = offs[i] + bsum[i >> 8];
        offs[i] = o;
        fill[i] = o;
    }
}
__global__ __launch_bounds__(256) void place_pack(const int* __restrict__ dst, const int* __restrict__ srcA,
                                                  const float* __restrict__ ea, const float* __restrict__ dis,
                                                  int* __restrict__ fill, int2* __restrict__ pack, int E) {
    int e = blockIdx.x * 256 + threadIdx.x;
    if (e < E) {
        int d = dst[e];
        int s = srcA[e];
        int pos = atomicAdd(&fill[d], 1);
        pack[pos] = make_int2(s, __float_as_int(dis[s] * ea[e]));
    }
}
// pure remap, no atomics (histograms derived in mapnode)
__global__ __launch_bounds__(256) void edgemap(
        const int* __restrict__ ei0, const int* __restrict__ ei1,
        const int* __restrict__ cmap,
        int* __restrict__ src2, int* __restrict__ dst2, int E)
{
    int e = blockIdx.x * 256 + threadIdx.x;
    if (e < E) {
        src2[e] = cmap[ei0[e]];
        dst2[e] = cmap[ei1[e]];
    }
}
__global__ __launch_bounds__(256) void seg_count(const int* __restrict__ map, int* __restrict__ cnt, int n) {
    int i = blockIdx.x * 256 + threadIdx.x;
    if (i < n) atomicAdd(&cnt[map[i]], 1);
}
__global__ __launch_bounds__(256) void place_idx(const int* __restrict__ map, int* __restrict__ fill,
                                                 int* __restrict__ list, int n) {
    int i = blockIdx.x * 256 + threadIdx.x;
    if (i < n) {
        int pos = atomicAdd(&fill[map[i]], 1);
        list[pos] = i;
    }
}
__global__ __launch_bounds__(256) void segmax_i32(const int* __restrict__ map, const int* __restrict__ vals,
                                                  int* __restrict__ out, int n) {
    int i = blockIdx.x * 256 + threadIdx.x;
    if (i < n) atomicMax(&out[map[i]], vals[i]);
}

// ---------------- gather-reduce (one wave per dst node; packed CSR; readlane broadcast) ----------------
#define EDGE_ITER(K, A0, A1) {                                                  \
    int s_ = __builtin_amdgcn_readlane(pv.x, (K));                              \
    float w_ = __int_as_float(__builtin_amdgcn_readlane(pv.y, (K)));            \
    unsigned hv_ = hrows[(size_t)s_ * 64 + lane];                               \
    float c_ = w_ * di;                                                         \
    A0 += c_ * __uint_as_float(hv_ << 16);                                      \
    A1 += c_ * __uint_as_float(hv_ & 0xFFFF0000u); }

// mpnn0 + residual: agg0[i] = bf16( dis^2*h[i] + sum + x[i] )
__global__ __launch_bounds__(256) void gather0(
        const unsigned short* __restrict__ h16, const float* __restrict__ x,
        const float* __restrict__ dis, const int* __restrict__ offs,
        const int* __restrict__ cnt, const int2* __restrict__ pack,
        unsigned* __restrict__ agg0)
{
    const int wid = (blockIdx.x * 256 + threadIdx.x) >> 6;
    if (wid >= N_NODES) return;
    const int lane = threadIdx.x & 63;
    const float di = dis[wid];
    const unsigned* hrows = (const unsigned*)h16;

    unsigned hself = hrows[(size_t)wid * 64 + lane];
    float a0 = di * di * __uint_as_float(hself << 16);
    float a1 = di * di * __uint_as_float(hself & 0xFFFF0000u);
    float b0 = 0.f, b1 = 0.f;

    const int base = offs[wid], n = cnt[wid];
    int k0 = 0;
    for (; k0 + 64 <= n; k0 += 64) {
        int2 pv = pack[base + k0 + lane];
        #pragma unroll
        for (int k = 0; k < 64; k += 2) {
            EDGE_ITER(k,     a0, a1);
            EDGE_ITER(k + 1, b0, b1);
        }
    }
    const int rem = n - k0;
    if (rem > 0) {
        int2 pv = (lane < rem) ? pack[base + k0 + lane] : make_int2(0, 0);
        #pragma unroll 4
        for (int k = 0; k < rem; ++k) EDGE_ITER(k, a0, a1);
    }
    a0 += b0; a1 += b1;

    float2 xv = *(const float2*)&x[(size_t)wid * DIM + lane * 2];
    agg0[(size_t)wid * 64 + lane] =
        ((unsigned)f2bf(a1 + xv.y) << 16) | (unsigned)f2bf(a0 + xv.x);
}

// mpnn2: agg2[i] = lrelu( dis^2*hm2[i] + sum )  (f32 row stores)
__global__ __launch_bounds__(256) void gather2(
        const unsigned short* __restrict__ hm2,
        const float* __restrict__ dis, const int* __restrict__ offs,
        const int* __restrict__ cnt, const int2* __restrict__ pack,
        float* __restrict__ agg2)
{
    const int wid = (blockIdx.x * 256 + threadIdx.x) >> 6;
    if (wid >= NPOOL1) return;
    const int lane = threadIdx.x & 63;
    const float di = dis[wid];
    const unsigned* hrows = (const unsigned*)hm2;

    unsigned hself = hrows[(size_t)wid * 64 + lane];
    float a0 = di * di * __uint_as_float(hself << 16);
    float a1 = di * di * __uint_as_float(hself & 0xFFFF0000u);
    float b0 = 0.f, b1 = 0.f;

    const int base = offs[wid], n = cnt[wid];
    int k0 = 0;
    for (; k0 + 64 <= n; k0 += 64) {
        int2 pv = pack[base + k0 + lane];
        #pragma unroll
        for (int k = 0; k < 64; k += 2) {
            EDGE_ITER(k,     a0, a1);
            EDGE_ITER(k + 1, b0, b1);
        }
    }
    const int rem = n - k0;
    if (rem > 0) {
        int2 pv = (lane < rem) ? pack[base + k0 + lane] : make_int2(0, 0);
        #pragma unroll 4
        for (int k = 0; k < rem; ++k) EDGE_ITER(k, a0, a1);
    }
    a0 += b0; a1 += b1;

    float2 o = make_float2(lrelu(a0), lrelu(a1));
    *(float2*)&agg2[(size_t)wid * DIM + lane * 2] = o;
}

// ---------------- pool gathers (atomic-free segment max via member lists) ----------------
__global__ __launch_bounds__(256) void pool1_gather(
        const unsigned* __restrict__ agg0, const float* __restrict__ x,
        const int* __restrict__ offsc, const int* __restrict__ cntc,
        const int* __restrict__ listc, unsigned* __restrict__ h2)
{
    const int c = (blockIdx.x * 256 + threadIdx.x) >> 6;
    if (c >= NPOOL0) return;
    const int lane = threadIdx.x & 63;
    const int base = offsc[c], n = cntc[c];
    float p0 = -INFINITY, p1 = -INFINITY, o0 = -INFINITY, o1 = -INFINITY;
    for (int k = 0; k < n; ++k) {
        const int node = listc[base + k];
        const unsigned hv = agg0[(size_t)node * 64 + lane];
        const float2 xv = *(const float2*)&x[(size_t)node * 128 + lane * 2];
        p0 = fmaxf(p0, lrelu(__uint_as_float(hv << 16)));
        p1 = fmaxf(p1, lrelu(__uint_as_float(hv & 0xFFFF0000u)));
        o0 = fmaxf(o0, xv.x);
        o1 = fmaxf(o1, xv.y);
    }
    p0 = (p0 == -INFINITY) ? 0.f : p0;
    p1 = (p1 == -INFINITY) ? 0.f : p1;
    o0 = (o0 == -INFINITY) ? 0.f : o0;
    o1 = (o1 == -INFINITY) ? 0.f : o1;
    h2[(size_t)c * 64 + lane] =
        ((unsigned)f2bf(p1 + o1) << 16) | (unsigned)f2bf(p0 + o0);
}

__global__ __launch_bounds__(256) void pool2_gather(
        const unsigned* __restrict__ h2,
        const int* __restrict__ offsd, const int* __restrict__ cntd,
        const int* __restrict__ listd, unsigned* __restrict__ x2)
{
    const int d = (blockIdx.x * 256 + threadIdx.x) >> 6;
    if (d >= NPOOL1) return;
    const int lane = threadIdx.x & 63;
    const int base = offsd[d], n = cntd[d];
    float m0 = -INFINITY, m1 = -INFINITY;
    for (int k = 0; k < n; ++k) {
        const int node = listd[base + k];
        const unsigned hv = h2[(size_t)node * 64 + lane];
        m0 = fmaxf(m0, lrelu(__uint_as_float(hv << 16)));
        m1 = fmaxf(m1, lrelu(__uint_as_float(hv & 0xFFFF0000u)));
    }
    m0 = (m0 == -INFINITY) ? 0.f : m0;
    m1 = (m1 == -INFINITY) ? 0.f : m1;
    x2[(size_t)d * 64 + lane] = ((unsigned)f2bf(m1) << 16) | (unsigned)f2bf(m0);
}

// ---------------- parallel global max pool over graph-sorted list ----------------
__global__ __launch_bounds__(256) void gpool_scan(
        const float* __restrict__ agg2, const int* __restrict__ listg,
        const int* __restrict__ pb2, float* __restrict__ gmax)
{
    const int wave = (blockIdx.x * 256 + threadIdx.x) >> 6;   // 0..511
    const int lane = threadIdx.x & 63;
    const int CH = (NPOOL1 + 511) / 512;                      // 49
    const int p0 = wave * CH;
    const int p1 = min(p0 + CH, NPOOL1);
    if (p0 >= NPOOL1) return;

    float m0 = -INFINITY, m1 = -INFINITY;
    int cur = -1;
    for (int p = p0; p < p1; ++p) {
        const int node = listg[p];
        const int g = pb2[node];                              // wave-uniform
        if (g != cur) {
            if (cur >= 0) {
                float* gp = &gmax[(size_t)cur * DIM + lane * 2];
                atomicMaxF(gp + 0, m0);
                atomicMaxF(gp + 1, m1);
            }
            cur = g; m0 = -INFINITY; m1 = -INFINITY;
        }
        const float2 v = *(const float2*)&agg2[(size_t)node * DIM + lane * 2];
        m0 = fmaxf(m0, v.x);
        m1 = fmaxf(m1, v.y);
    }
    float* gp = &gmax[(size_t)cur * DIM + lane * 2];
    atomicMaxF(gp + 0, m0);
    atomicMaxF(gp + 1, m1);
}

// ---------------- head ----------------
__global__ __launch_bounds__(128) void head(
        const float* __restrict__ gmax, const float* __restrict__ energy,
        const float* __restrict__ emb_w, const float* __restrict__ emb_b,
        const float* __restrict__ emb_g, const float* __restrict__ emb_be,
        const float* __restrict__ lw1, const float* __restrict__ lb1,
        const float* __restrict__ lg, const float* __restrict__ lbe,
        const float* __restrict__ lw2, const float* __restrict__ lb2,
        float* __restrict__ out)
{
    const int g = blockIdx.x;
    const int t = threadIdx.x;
    __shared__ float z[136];
    __shared__ float red[128];

    {
        float v = gmax[(size_t)g * DIM + t];
        z[t] = (v == -INFINITY) ? 0.f : v;
    }
    if (t < 8) {
        float s = 0.f;
        #pragma unroll
        for (int k = 0; k < 21; ++k) s += energy[g * 21 + k] * emb_w[t * 21 + k];
        s = (s + emb_b[t]) * emb_g[t] + emb_be[t];
        z[128 + t] = lrelu(s);
    }
    __syncthreads();
    float s = 0.f;
    #pragma unroll 8
    for (int k = 0; k < 136; ++k) s += z[k] * lw1[t * 136 + k];
    float z2 = lrelu((s + lb1[t]) * lg[t] + lbe[t]);
    red[t] = z2 * lw2[t];
    __syncthreads();
    if (t == 0) {
        float acc = lb2[0];
        for (int k = 0; k < 128; ++k) acc += red[k];
        out[g] = acc;
    }
}

extern "C" void kernel_launch(void* const* d_in, const int* in_sizes, int n_in,
                              void* d_out, int out_size, void* d_ws, size_t ws_size,
                              hipStream_t stream) {
    const float* x        = (const float*)d_in[0];
    const float* edge_attr= (const float*)d_in[1];
    const float* energy   = (const float*)d_in[2];
    const float* w0a = (const float*)d_in[3];
    const float* b0a = (const float*)d_in[4];
    const float* g0  = (const float*)d_in[5];
    const float* be0 = (const float*)d_in[6];
    const float* w0b = (const float*)d_in[7];
    const float* b0b = (const float*)d_in[8];
    const float* w2a = (const float*)d_in[15];
    const float* b2a = (const float*)d_in[16];
    const float* g2  = (const float*)d_in[17];
    const float* be2 = (const float*)d_in[18];
    const float* w2b = (const float*)d_in[19];
    const float* b2b = (const float*)d_in[20];
    const float* emb_w  = (const float*)d_in[21];
    const float* emb_b  = (const float*)d_in[22];
    const float* emb_g  = (const float*)d_in[23];
    const float* emb_be = (const float*)d_in[24];
    const float* lw1 = (const float*)d_in[25];
    const float* lb1 = (const float*)d_in[26];
    const float* lg  = (const float*)d_in[27];
    const float* lbe = (const float*)d_in[28];
    const float* lw2 = (const float*)d_in[29];
    const float* lb2 = (const float*)d_in[30];
    const int* ei0   = (const int*)d_in[31];
    const int* ei1   = ei0 + N_EDGES;
    const int* batch = (const int*)d_in[32];
    const int* c0    = (const int*)d_in[33];
    const int* c1    = (const int*)d_in[34];
    float* out = (float*)d_out;

    // ---- workspace layout (peak ~87.8 MB) ----
    char* ws = (char*)d_ws;
    unsigned short* h16 = (unsigned short*)(ws + 0);         // [N,128] bf16 (dead after gather0)
    int*   src2  = (int*)(ws + 0);                           // [E] (alias h16)
    int*   dst2  = (int*)(ws + 6400000);                     // [E]
    float* agg2  = (float*)(ws + 12800000);                  // [N1,128] f32
    unsigned* agg0 = (unsigned*)(ws + 25600000);             // [N,128] bf16 (dead after pool1_gather)
    unsigned short* hm2 = (unsigned short*)(ws + 25600000);  // [N1,128] bf16 (alias agg0)
    int2*  pack0 = (int2*)(ws + 51200000);                   // [E]
    int2*  pack2 = (int2*)(ws + 51200000);                   // alias
    unsigned* h2 = (unsigned*)(ws + 64000000);               // [N0,128] bf16
    unsigned* x2 = (unsigned*)(ws + 76800000);               // [N1,128] bf16
    float* deg0  = (float*)(ws + 83200000);                  // [N]
    float* deg2  = (float*)(ws + 83600000);                  // [N1]
    // ---- contiguous zero-init region (single memset) ----
    char*  zbase = ws + 83700000;
    int*   cnt0  = (int*)(ws + 83700000);                    // [N]
    int*   cnt2  = (int*)(ws + 84100000);                    // [N1]
    int*   cntc  = (int*)(ws + 84200000);                    // [N0]
    int*   cntd  = (int*)(ws + 84400000);                    // [N1]
    int*   cntg  = (int*)(ws + 84500000);                    // [64]
    int*   pb    = (int*)(ws + 84500256);                    // [N0]
    int*   pb2   = (int*)(ws + 84700256);                    // [N1]
    const size_t ZBYTES = 84800256 - 83700000;               // 1,100,256 B
    // ---- rest of bookkeeping ----
    int*   offs0 = (int*)(ws + 84800256);
    int*   fill0 = (int*)(ws + 85200256);
    int*   offsc = (int*)(ws + 85600256);
    int*   fillc = (int*)(ws + 85800256);
    int*   listc = (int*)(ws + 86000256);                    // [N]
    int*   offsd = (int*)(ws + 86400256);
    int*   filld = (int*)(ws + 86500256);
    int*   listd = (int*)(ws + 86600256);                    // [N0]
    int*   offs2 = (int*)(ws + 86800256);
    int*   fill2 = (int*)(ws + 86900256);
    int*   offsg = (int*)(ws + 87000256);
    int*   fillg = (int*)(ws + 87000512);
    int*   listg = (int*)(ws + 87000768);                    // [N1]
    int*   bsum  = (int*)(ws + 87100768);                    // [<=512]
    int*   cmap  = (int*)(ws + 87103000);                    // [N]
    unsigned short* w0a16 = (unsigned short*)(ws + 87503000);
    unsigned short* w0b16 = (unsigned short*)(ws + 87535768);
    unsigned short* w2a16 = (unsigned short*)(ws + 87568536);
    unsigned short* w2b16 = (unsigned short*)(ws + 87634072);
    float* gmax  = (float*)(ws + 87699608);                  // [64,128] f32

    (void)in_sizes; (void)n_in; (void)out_size; (void)ws_size;

    const int NB0 = (N_NODES + 255) / 256;   // 391
    const int NBC = (NPOOL0 + 255) / 256;    // 196
    const int NB1 = (NPOOL1 + 255) / 256;    // 98
    const int NBE = (N_EDGES + 255) / 256;

    // ---- consolidated init ----
    hipMemsetAsync(zbase, 0, ZBYTES, stream);
    init_f<<<(N_NODES + NPOOL1 + NGRAPH * DIM + 255) / 256, 256, 0, stream>>>(deg0, deg2, gmax);
    conv_weights<<<384, 256, 0, stream>>>(w0a, w0b, w2a, w2b, w0a16, w0b16, w2a16, w2b16);

    // ---- mpnn0: MFMA MLP + CSR(pack) + gather ----
    mlp_mfma<128, 128, false><<<(N_NODES + 63) / 64, 256, 0, stream>>>(
        x, N_NODES, w0a16, b0a, g0, be0, w0b16, b0b, h16);
    count0<<<NBE, 256, 0, stream>>>(ei0, ei1, deg0, cnt0, N_EDGES);
    mapnode<<<NB0, 256, 0, stream>>>(c0, c1, deg0, cnt0, cmap, deg2, cnt2, N_NODES);
    rsqrt_ip<<<NB0, 256, 0, stream>>>(deg0, N_NODES);
    scan_blk<<<NB0, 256, 0, stream>>>(cnt0, offs0, bsum, N_NODES);
    scan_top<<<1, 512, 0, stream>>>(bsum, NB0);
    scan_add<<<NB0, 256, 0, stream>>>(offs0, bsum, fill0, N_NODES);
    place_pack<<<NBE, 256, 0, stream>>>(ei1, ei0, edge_attr, deg0, fill0, pack0, N_EDGES);
    gather0<<<(N_NODES * 64) / 256, 256, 0, stream>>>(h16, x, deg0, offs0, cnt0, pack0, agg0);

    // ---- pool1 via cluster0 member lists ----
    seg_count<<<NB0, 256, 0, stream>>>(c0, cntc, N_NODES);
    scan_blk<<<NBC, 256, 0, stream>>>(cntc, offsc, bsum, NPOOL0);
    scan_top<<<1, 512, 0, stream>>>(bsum, NBC);
    scan_add<<<NBC, 256, 0, stream>>>(offsc, bsum, fillc, NPOOL0);
    place_idx<<<NB0, 256, 0, stream>>>(c0, fillc, listc, N_NODES);
    segmax_i32<<<NB0, 256, 0, stream>>>(c0, batch, pb, N_NODES);
    pool1_gather<<<(NPOOL0 * 64) / 256, 256, 0, stream>>>(agg0, x, offsc, cntc, listc, h2);

    // ---- pool2 via cluster1 member lists ----
    seg_count<<<NBC, 256, 0, stream>>>(c1, cntd, NPOOL0);
    scan_blk<<<NB1, 256, 0, stream>>>(cntd, offsd, bsum, NPOOL1);
    scan_top<<<1, 512, 0, stream>>>(bsum, NB1);
    scan_add<<<NB1, 256, 0, stream>>>(offsd, bsum, filld, NPOOL1);
    place_idx<<<NBC, 256, 0, stream>>>(c1, filld, listd, NPOOL0);
    segmax_i32<<<NBC, 256, 0, stream>>>(c1, pb, pb2, NPOOL0);
    pool2_gather<<<(NPOOL1 * 64) / 256, 256, 0, stream>>>(h2, offsd, cntd, listd, x2);

    // ---- mpnn2: remap + MFMA MLP + CSR(pack) + gather ----
    edgemap<<<NBE, 256, 0, stream>>>(ei0, ei1, cmap, src2, dst2, N_EDGES);
    rsqrt_ip<<<NB1, 256, 0, stream>>>(deg2, NPOOL1);
    scan_blk<<<NB1, 256, 0, stream>>>(cnt2, offs2, bsum, NPOOL1);
    scan_top<<<1, 512, 0, stream>>>(bsum, NB1);
    scan_add<<<NB1, 256, 0, stream>>>(offs2, bsum, fill2, NPOOL1);
    mlp_mfma<128, 256, true><<<(NPOOL1 + 63) / 64, 256, 0, stream>>>(
        x2, NPOOL1, w2a16, b2a, g2, be2, w2b16, b2b, hm2);
    place_pack<<<NBE, 256, 0, stream>>>(dst2, src2, edge_attr, deg2, fill2, pack2, N_EDGES);
    gather2<<<(NPOOL1 * 64) / 256, 256, 0, stream>>>(hm2, deg2, offs2, cnt2, pack2, agg2);

    // ---- graph buckets + parallel gpool + head ----
    seg_count<<<NB1, 256, 0, stream>>>(pb2, cntg, NPOOL1);
    scan_blk<<<1, 256, 0, stream>>>(cntg, offsg, bsum, NGRAPH);
    scan_top<<<1, 512, 0, stream>>>(bsum, 1);
    scan_add<<<1, 256, 0, stream>>>(offsg, bsum, fillg, NGRAPH);
    place_idx<<<NB1, 256, 0, stream>>>(pb2, fillg, listg, NPOOL1);
    gpool_scan<<<128, 256, 0, stream>>>(agg2, listg, pb2, gmax);
    head<<<NGRAPH, 128, 0, stream>>>(gmax, energy, emb_w, emb_b, emb_g, emb_be,
                                     lw1, lb1, lg, lbe, lw2, lb2, out);
}